// Round 1
// baseline (9142.155 us; speedup 1.0000x reference)
//
#include <hip/hip_runtime.h>
#include <math.h>

#define T 4
#define HH 64
#define HE 16
#define HD 128
#define IN_EDGE (HH*2 + 1 + HE)   // 145
#define IN_NODE (HH + HD)         // 192
#define EPSF 1e-8f

#define TE 16                     // edges per block (edge kernel)
#define TN 16                     // nodes per block (node kernel)
#define ROWS 64                   // TE*T merged rows per tile
#define STRIDE 68                 // LDS row stride (floats): 16B-aligned rows, 4*68 % 32 != 0

__device__ __forceinline__ float silu_f(float v) {
    return v / (1.f + __expf(-v));
}

// 64x8-per-... : each thread computes a 4-row x 8-col sub-tile of a 64 x 128 output.
// A is k-major in LDS: A[k][row], stride 68. W is row-major [K][128].
template<int K>
__device__ __forceinline__ void gemm_tile8(const float (*A)[STRIDE],
                                           const float* __restrict__ W,
                                           const float* __restrict__ bias,
                                           int r0, int j0, float acc[4][8])
{
    float4 bb0 = *(const float4*)&bias[j0];
    float4 bb1 = *(const float4*)&bias[j0 + 4];
    #pragma unroll
    for (int i = 0; i < 4; ++i) {
        acc[i][0] = bb0.x; acc[i][1] = bb0.y; acc[i][2] = bb0.z; acc[i][3] = bb0.w;
        acc[i][4] = bb1.x; acc[i][5] = bb1.y; acc[i][6] = bb1.z; acc[i][7] = bb1.w;
    }
    #pragma unroll 1
    for (int k = 0; k < K; ++k) {
        float4 a4 = *(const float4*)&A[k][r0];
        float4 w0 = *(const float4*)&W[k * HD + j0];
        float4 w1 = *(const float4*)&W[k * HD + j0 + 4];
        float av[4] = {a4.x, a4.y, a4.z, a4.w};
        float wv[8] = {w0.x, w0.y, w0.z, w0.w, w1.x, w1.y, w1.z, w1.w};
        #pragma unroll
        for (int i = 0; i < 4; ++i)
            #pragma unroll
            for (int u = 0; u < 8; ++u)
                acc[i][u] = fmaf(av[i], wv[u], acc[i][u]);
    }
}

// -------------------- Edge kernel --------------------
// Per block: 16 edges -> 64 merged rows.
//   m_in[r][0:64]=h[row], [64:128]=h[col], [128]=|x_ij|^2, [129:145]=edge_attr
//   y1 = silu(m_in @ w1 + b1); y2 = silu(y1 @ w2 + b2)   (= m_ij)
//   atomicAdd m_i[row_node][j][t] += y2
//   c1 = silu(y2 @ cw1 + cb1); c = (c1 @ cw2 + cb2) / (sqrt(n2+eps)+1)
//   atomicAdd agg[row_node][axis][t] += c * x_ij; cnt[row_node] += 1
__launch_bounds__(256, 2)
__global__ void edge_kernel(const float* __restrict__ x,
                            const float* __restrict__ h,
                            const int*   __restrict__ ei,
                            const float* __restrict__ ea,
                            const float* __restrict__ w1,  const float* __restrict__ b1,
                            const float* __restrict__ w2,  const float* __restrict__ b2,
                            const float* __restrict__ cw1, const float* __restrict__ cb1,
                            const float* __restrict__ cw2, const float* __restrict__ cb2,
                            float* __restrict__ m_i,
                            float* __restrict__ agg,
                            float* __restrict__ cnt,
                            int N, int E)
{
    __shared__ float sA[IN_EDGE][STRIDE];   // k-major input / later y2^T
    __shared__ float sB[HD][STRIDE];        // y1^T / later c1^T
    __shared__ float sXij[TE][12];          // x_ij per edge [axis*4+t]
    __shared__ float sNorm[ROWS];
    __shared__ int   sNode[TE];

    const int tid = threadIdx.x;
    const int e0  = blockIdx.x * TE;

    // ---- Phase 1: stage m_in^T ----
    if (tid < TE) {
        int e = e0 + tid;
        sNode[tid] = (e < E) ? ei[e] : 0;
    }
    {
        const int d = tid >> 2, t = tid & 3;
        for (int le = 0; le < TE; ++le) {
            int e = e0 + le;
            if (e >= E) break;
            int rn = ei[e];
            int cn = ei[E + e];
            int r = le * 4 + t;
            sA[d][r]      = h[(size_t)rn * (HH * T) + tid];
            sA[HH + d][r] = h[(size_t)cn * (HH * T) + tid];
        }
    }
    // edge_attr: 64 floats/edge, 4 edges per pass
    #pragma unroll
    for (int pass = 0; pass < 4; ++pass) {
        int le = pass * 4 + (tid >> 6);
        int i  = tid & 63;
        int e  = e0 + le;
        if (e < E) {
            int d = i >> 2, t = i & 3;
            sA[1 + 2 * HH + d][le * 4 + t] = ea[(size_t)e * (HE * T) + i];
        }
    }
    // x_ij
    {
        int le = tid >> 4;
        int i  = tid & 15;
        if (i < 12) {
            int e = e0 + le;
            float d = 0.f;
            if (e < E) {
                int rn = ei[e], cn = ei[E + e];
                d = x[(size_t)rn * 12 + i] - x[(size_t)cn * 12 + i];
            }
            sXij[le][i] = d;
        }
    }
    __syncthreads();
    if (tid < ROWS) {
        int le = tid >> 2, t = tid & 3;
        float a0 = sXij[le][t], a1 = sXij[le][4 + t], a2 = sXij[le][8 + t];
        float n2 = a0 * a0 + a1 * a1 + a2 * a2;
        sNorm[tid] = n2;
        sA[2 * HH][tid] = n2;
    }
    __syncthreads();

    const int jg = tid & 15;
    const int rg = tid >> 4;
    const int r0 = rg * 4;
    const int j0 = jg * 8;

    // ---- Layer 1 ----
    {
        float acc[4][8];
        gemm_tile8<IN_EDGE>(sA, w1, b1, r0, j0, acc);
        #pragma unroll
        for (int u = 0; u < 8; ++u) {
            float4 v;
            v.x = silu_f(acc[0][u]); v.y = silu_f(acc[1][u]);
            v.z = silu_f(acc[2][u]); v.w = silu_f(acc[3][u]);
            *(float4*)&sB[j0 + u][r0] = v;
        }
    }
    __syncthreads();

    // ---- Layer 2 (y2 = m_ij) + m_i atomics ----
    {
        float acc[4][8];
        gemm_tile8<HD>(sB, w2, b2, r0, j0, acc);
        // rows r0..r0+3 are the 4 t's of edge 'rg'
        const int  node  = sNode[rg];
        const bool valid = (e0 + rg) < E;
        float* mb = m_i + (size_t)node * (HD * T);
        #pragma unroll
        for (int u = 0; u < 8; ++u) {
            float y0 = silu_f(acc[0][u]);
            float y1v = silu_f(acc[1][u]);
            float y2v = silu_f(acc[2][u]);
            float y3v = silu_f(acc[3][u]);
            *(float4*)&sA[j0 + u][r0] = make_float4(y0, y1v, y2v, y3v);
            if (valid) {
                atomicAdd(mb + (j0 + u) * 4 + 0, y0);
                atomicAdd(mb + (j0 + u) * 4 + 1, y1v);
                atomicAdd(mb + (j0 + u) * 4 + 2, y2v);
                atomicAdd(mb + (j0 + u) * 4 + 3, y3v);
            }
        }
    }
    __syncthreads();

    // ---- Coord layer 1 ----
    {
        float acc[4][8];
        gemm_tile8<HD>(sA, cw1, cb1, r0, j0, acc);
        #pragma unroll
        for (int u = 0; u < 8; ++u) {
            float4 v;
            v.x = silu_f(acc[0][u]); v.y = silu_f(acc[1][u]);
            v.z = silu_f(acc[2][u]); v.w = silu_f(acc[3][u]);
            *(float4*)&sB[j0 + u][r0] = v;
        }
    }
    __syncthreads();

    // ---- Coord layer 2 (128 -> 1) + agg/cnt atomics ----
    if (tid < ROWS) {
        int r = tid;
        float dot = cb2[0];
        #pragma unroll 8
        for (int k = 0; k < HD; ++k)
            dot = fmaf(sB[k][r], cw2[k], dot);
        int le = r >> 2, t = r & 3;
        int e = e0 + le;
        if (e < E) {
            float denom = sqrtf(sNorm[r] + EPSF) + 1.f;
            float c = dot / denom;
            int node = sNode[le];
            atomicAdd(&agg[(size_t)node * 12 + 0 + t], c * sXij[le][0 + t]);
            atomicAdd(&agg[(size_t)node * 12 + 4 + t], c * sXij[le][4 + t]);
            atomicAdd(&agg[(size_t)node * 12 + 8 + t], c * sXij[le][8 + t]);
            if (t == 0) atomicAdd(&cnt[node], 1.f);
        }
    }
}

// -------------------- Node kernel --------------------
// h_new = silu([h | m_i] @ nw1 + nb1) @ nw2 + nb2
__launch_bounds__(256, 1)
__global__ void node_kernel(const float* __restrict__ h,
                            const float* __restrict__ m_i,
                            const float* __restrict__ nw1, const float* __restrict__ nb1,
                            const float* __restrict__ nw2, const float* __restrict__ nb2,
                            float* __restrict__ out_h,
                            int N)
{
    __shared__ float sA[IN_NODE][STRIDE];   // 192 x 68
    __shared__ float sB[HD][STRIDE];

    const int tid = threadIdx.x;
    const int n0  = blockIdx.x * TN;

    for (int i = tid; i < TN * HH * T; i += 256) {
        int ln = i >> 8, rem = i & 255;
        int d = rem >> 2, t = rem & 3;
        if (n0 + ln < N) sA[d][ln * 4 + t] = h[(size_t)(n0 + ln) * (HH * T) + rem];
    }
    for (int i = tid; i < TN * HD * T; i += 256) {
        int ln = i >> 9, rem = i & 511;
        int d = rem >> 2, t = rem & 3;
        if (n0 + ln < N) sA[HH + d][ln * 4 + t] = m_i[(size_t)(n0 + ln) * (HD * T) + rem];
    }
    __syncthreads();

    const int jg = tid & 15;
    const int rg = tid >> 4;
    const int r0 = rg * 4;

    // layer 1: K=192 -> 128 cols, silu
    {
        const int j0 = jg * 8;
        float acc[4][8];
        gemm_tile8<IN_NODE>(sA, nw1, nb1, r0, j0, acc);
        #pragma unroll
        for (int u = 0; u < 8; ++u) {
            float4 v;
            v.x = silu_f(acc[0][u]); v.y = silu_f(acc[1][u]);
            v.z = silu_f(acc[2][u]); v.w = silu_f(acc[3][u]);
            *(float4*)&sB[j0 + u][r0] = v;
        }
    }
    __syncthreads();

    // layer 2: K=128 -> 64 cols, no activation; write straight to out
    {
        const int j0 = jg * 4;   // 16 groups x 4 cols
        float acc[4][4];
        float4 bb = *(const float4*)&nb2[j0];
        #pragma unroll
        for (int i = 0; i < 4; ++i) {
            acc[i][0] = bb.x; acc[i][1] = bb.y; acc[i][2] = bb.z; acc[i][3] = bb.w;
        }
        #pragma unroll 1
        for (int k = 0; k < HD; ++k) {
            float4 a4 = *(const float4*)&sB[k][r0];
            float4 w4 = *(const float4*)&nw2[k * HH + j0];
            float av[4] = {a4.x, a4.y, a4.z, a4.w};
            float wv[4] = {w4.x, w4.y, w4.z, w4.w};
            #pragma unroll
            for (int i = 0; i < 4; ++i)
                #pragma unroll
                for (int u = 0; u < 4; ++u)
                    acc[i][u] = fmaf(av[i], wv[u], acc[i][u]);
        }
        const int ln = rg;          // rows r0..r0+3 = 4 t's of node rg
        if (n0 + ln < N) {
            float* ob = out_h + (size_t)(n0 + ln) * (HH * T);
            #pragma unroll
            for (int u = 0; u < 4; ++u) {
                ob[(j0 + u) * 4 + 0] = acc[0][u];
                ob[(j0 + u) * 4 + 1] = acc[1][u];
                ob[(j0 + u) * 4 + 2] = acc[2][u];
                ob[(j0 + u) * 4 + 3] = acc[3][u];
            }
        }
    }
}

// -------------------- Coord update --------------------
__global__ void coord_update(const float* __restrict__ x,
                             const float* __restrict__ agg,
                             const float* __restrict__ cnt,
                             float* __restrict__ out_x,
                             int N)
{
    int i = blockIdx.x * 256 + threadIdx.x;
    if (i < N * 12) {
        int n = i / 12;
        out_x[i] = x[i] + agg[i] / fmaxf(cnt[n], 1.f);
    }
}

extern "C" void kernel_launch(void* const* d_in, const int* in_sizes, int n_in,
                              void* d_out, int out_size, void* d_ws, size_t ws_size,
                              hipStream_t stream)
{
    const float* x   = (const float*)d_in[0];
    const float* h   = (const float*)d_in[1];
    const int*   ei  = (const int*)d_in[2];
    const float* ea  = (const float*)d_in[3];
    // d_in[4] = batch (unused)
    const float* w1  = (const float*)d_in[5];
    const float* b1  = (const float*)d_in[6];
    const float* w2  = (const float*)d_in[7];
    const float* b2  = (const float*)d_in[8];
    const float* cw1 = (const float*)d_in[9];
    const float* cb1 = (const float*)d_in[10];
    const float* cw2 = (const float*)d_in[11];
    const float* cb2 = (const float*)d_in[12];
    const float* nw1 = (const float*)d_in[13];
    const float* nb1 = (const float*)d_in[14];
    const float* nw2 = (const float*)d_in[15];
    const float* nb2 = (const float*)d_in[16];

    const int N = in_sizes[0] / 12;      // x is [N,3,T]
    const int E = in_sizes[2] / 2;       // edge_index is [2,E]

    float* m_i = (float*)d_ws;                         // N*HD*T
    float* agg = m_i + (size_t)N * HD * T;             // N*12
    float* cnt = agg + (size_t)N * 12;                 // N
    size_t zero_bytes = ((size_t)N * (HD * T + 12 + 1)) * sizeof(float);
    hipMemsetAsync(d_ws, 0, zero_bytes, stream);

    float* out_x = (float*)d_out;
    float* out_h = out_x + (size_t)N * 3 * T;

    int nblkA = (E + TE - 1) / TE;
    edge_kernel<<<nblkA, 256, 0, stream>>>(x, h, ei, ea, w1, b1, w2, b2,
                                           cw1, cb1, cw2, cb2, m_i, agg, cnt, N, E);
    int nblkB = (N + TN - 1) / TN;
    node_kernel<<<nblkB, 256, 0, stream>>>(h, m_i, nw1, nb1, nw2, nb2, out_h, N);
    int nblkC = (N * 12 + 255) / 256;
    coord_update<<<nblkC, 256, 0, stream>>>(x, agg, cnt, out_x, N);
}

// Round 2
// 2596.189 us; speedup vs baseline: 3.5214x; 3.5214x over previous
//
#include <hip/hip_runtime.h>
#include <math.h>

#define T 4
#define HH 64
#define HE 16
#define HD 128
#define EPSF 1e-8f

#define E_EDGES 32
#define E_M 128
#define LDA 168     // edge-kernel k-stride (bf16 elems): 336B = 84 banks == 20 mod 32 -> conflict-free b128
#define LDB 136     // activation buffer stride: 272B = 68 banks == 4 mod 32 -> conflict-free b128
#define N_NODES 32
#define LDAN 200    // node-kernel k-stride: 400B = 100 banks == 4 mod 32 -> conflict-free b128

using frag8 = __attribute__((ext_vector_type(8))) short;
using f32x4 = __attribute__((ext_vector_type(4))) float;

__device__ __forceinline__ float silu_f(float v) { return v / (1.f + __expf(-v)); }

__device__ __forceinline__ unsigned short f2b(float f) {
    union { float f; unsigned u; } v; v.f = f;
    unsigned r = v.u + 0x7FFF + ((v.u >> 16) & 1);   // RNE
    return (unsigned short)(r >> 16);
}
__device__ __forceinline__ unsigned pk2(float a, float b) {
    return (unsigned)f2b(a) | ((unsigned)f2b(b) << 16);
}
__device__ __forceinline__ uint4 pk8(const float* v) {
    uint4 r;
    r.x = pk2(v[0], v[1]); r.y = pk2(v[2], v[3]);
    r.z = pk2(v[4], v[5]); r.w = pk2(v[6], v[7]);
    return r;
}

// ---------------- weight prep: fp32 -> bf16, transposed to [n][k] ----------------
// wb layout (bf16 elems): w1b [128][160] @0 (k: 0..127 h_row|h_col, 128..143 ea, 144 n2, 145.. 0)
//                         w2b [128][128] @20480, cw1b [128][128] @36864,
//                         nw1b [128][192] @53248, nw2b [64][128] @77824   (total 86016)
__global__ void prep_weights(const float* __restrict__ w1, const float* __restrict__ w2,
                             const float* __restrict__ cw1, const float* __restrict__ nw1,
                             const float* __restrict__ nw2, unsigned short* __restrict__ wb)
{
    int i = blockIdx.x * 256 + threadIdx.x;
    if (i < 20480) {
        int n = i / 160, k = i - n * 160;
        float v;
        if (k < 128)      v = w1[k * 128 + n];
        else if (k < 144) v = w1[(129 + (k - 128)) * 128 + n];   // ea dims
        else if (k == 144) v = w1[128 * 128 + n];                 // n2 dim
        else              v = 0.f;
        wb[i] = f2b(v);
    } else if (i < 36864) {
        int j = i - 20480; int n = j >> 7, k = j & 127;
        wb[i] = f2b(w2[k * 128 + n]);
    } else if (i < 53248) {
        int j = i - 36864; int n = j >> 7, k = j & 127;
        wb[i] = f2b(cw1[k * 128 + n]);
    } else if (i < 77824) {
        int j = i - 53248; int n = j / 192, k = j - n * 192;
        wb[i] = f2b(nw1[k * 128 + n]);
    } else if (i < 86016) {
        int j = i - 77824; int n = j >> 7, k = j & 127;
        wb[i] = f2b(nw2[k * 64 + n]);
    }
}

// ---------------- edge kernel: 32 edges (128 rows) per block, 512 threads ----------------
__global__ __launch_bounds__(512, 1)
void edge_kernel(const float* __restrict__ x, const float* __restrict__ h,
                 const int* __restrict__ ei, const float* __restrict__ ea,
                 const unsigned short* __restrict__ w1b,
                 const unsigned short* __restrict__ w2b,
                 const unsigned short* __restrict__ cw1b,
                 const float* __restrict__ b1, const float* __restrict__ b2,
                 const float* __restrict__ cb1, const float* __restrict__ cb2,
                 const float* __restrict__ cw2,
                 float* __restrict__ m_i, float* __restrict__ agg, float* __restrict__ cnt,
                 int N, int E)
{
    __shared__ unsigned short sA[E_M * LDA];   // m_in (K=160), later y2 (K=128)
    __shared__ unsigned short sW[E_M * LDA];   // current layer weights [n][k]
    __shared__ unsigned short sB[E_M * LDB];   // y1
    __shared__ float sXij[E_EDGES * 12];
    __shared__ float sNorm[E_M];
    __shared__ int   sNode[E_EDGES];

    const int tid = threadIdx.x;
    const int e0  = blockIdx.x * E_EDGES;

    // stage w1 into sW (2560 x 16B chunks)
    for (int c = tid; c < 2560; c += 512) {
        int row = c / 20, kc = (c - row * 20) * 8;
        *(uint4*)&sW[row * LDA + kc] = *(const uint4*)&w1b[row * 160 + kc];
    }
    if (tid < E_EDGES) {
        int e = e0 + tid;
        sNode[tid] = (e < E) ? ei[e] : 0;
    }
    if (tid < E_EDGES * 12) {
        int le = tid / 12, i = tid - le * 12;     // i = axis*4 + t
        int e = e0 + le;
        float d = 0.f;
        if (e < E) { int rn = ei[e], cn = ei[E + e]; d = x[rn * 12 + i] - x[cn * 12 + i]; }
        sXij[tid] = d;
    }
    // h rows: threads 0..255 -> h[row] (k 0..63), 256..511 -> h[col] (k 64..127)
    {
        int half = tid >> 8;
        int t8 = tid & 255;
        int le = t8 >> 3, d0 = (t8 & 7) * 8;
        int e = e0 + le;
        if (e < E) {
            int node = ei[half ? (E + e) : e];
            const float4* hp = (const float4*)(h + (size_t)node * 256);
            float4 hv[8];
            #pragma unroll
            for (int q = 0; q < 8; ++q) hv[q] = hp[d0 + q];
            #pragma unroll
            for (int t = 0; t < 4; ++t) {
                float vv[8];
                #pragma unroll
                for (int q = 0; q < 8; ++q) vv[q] = ((const float*)&hv[q])[t];
                *(uint4*)&sA[(le * 4 + t) * LDA + half * 64 + d0] = pk8(vv);
            }
        }
    }
    // edge_attr: k 128..143
    if (tid < 128) {
        int le = tid >> 2, eh0 = (tid & 3) * 4;
        int e = e0 + le;
        if (e < E) {
            const float4* ap = (const float4*)(ea + (size_t)e * 64);
            float4 av[4];
            #pragma unroll
            for (int q = 0; q < 4; ++q) av[q] = ap[eh0 + q];
            #pragma unroll
            for (int t = 0; t < 4; ++t) {
                uint2 u;
                u.x = pk2(((const float*)&av[0])[t], ((const float*)&av[1])[t]);
                u.y = pk2(((const float*)&av[2])[t], ((const float*)&av[3])[t]);
                *(uint2*)&sA[(le * 4 + t) * LDA + 128 + eh0] = u;
            }
        }
    }
    __syncthreads();
    // n2 at k=144, zero-pad k 145..159
    if (tid < E_M) {
        int le = tid >> 2, t = tid & 3;
        float a0 = sXij[le * 12 + t], a1 = sXij[le * 12 + 4 + t], a2 = sXij[le * 12 + 8 + t];
        float n2 = a0 * a0 + a1 * a1 + a2 * a2;
        sNorm[tid] = n2;
        uint4 z = {0, 0, 0, 0};
        *(uint4*)&sA[tid * LDA + 144] = z;
        *(uint4*)&sA[tid * LDA + 152] = z;
        sA[tid * LDA + 144] = f2b(n2);
    }
    // prefetch w2 into regs (hides L2 behind barrier + layer1)
    uint4 wp[4];
    #pragma unroll
    for (int i = 0; i < 4; ++i) {
        int c = tid + i * 512;
        wp[i] = *(const uint4*)&w2b[(c >> 4) * 128 + (c & 15) * 8];
    }
    __syncthreads();

    const int lane = tid & 63;
    const int wave = tid >> 6;
    const int lrow = lane & 15;
    const int quad = lane >> 4;
    const int mbase = wave * 16;

    // ---- layer 1: [128 x 160] @ [160 x 128] ----
    f32x4 acc[8];
    #pragma unroll
    for (int nt = 0; nt < 8; ++nt) acc[nt] = (f32x4){0.f, 0.f, 0.f, 0.f};
    #pragma unroll
    for (int kb = 0; kb < 5; ++kb) {
        frag8 a = *(const frag8*)&sA[(mbase + lrow) * LDA + kb * 32 + quad * 8];
        #pragma unroll
        for (int nt = 0; nt < 8; ++nt) {
            frag8 b = *(const frag8*)&sW[(nt * 16 + lrow) * LDA + kb * 32 + quad * 8];
            acc[nt] = __builtin_amdgcn_mfma_f32_16x16x32_bf16(a, b, acc[nt], 0, 0, 0);
        }
    }
    #pragma unroll
    for (int nt = 0; nt < 8; ++nt) {
        int col = nt * 16 + lrow;
        float bias = b1[col];
        #pragma unroll
        for (int r = 0; r < 4; ++r) {
            float v = silu_f(acc[nt][r] + bias);
            sB[(mbase + quad * 4 + r) * LDB + col] = f2b(v);
        }
    }
    __syncthreads();
    // install w2, prefetch cw1
    #pragma unroll
    for (int i = 0; i < 4; ++i) {
        int c = tid + i * 512;
        *(uint4*)&sW[(c >> 4) * LDA + (c & 15) * 8] = wp[i];
    }
    #pragma unroll
    for (int i = 0; i < 4; ++i) {
        int c = tid + i * 512;
        wp[i] = *(const uint4*)&cw1b[(c >> 4) * 128 + (c & 15) * 8];
    }
    __syncthreads();

    // ---- layer 2: y2 = silu(y1 @ w2 + b2) ----
    #pragma unroll
    for (int nt = 0; nt < 8; ++nt) acc[nt] = (f32x4){0.f, 0.f, 0.f, 0.f};
    #pragma unroll
    for (int kb = 0; kb < 4; ++kb) {
        frag8 a = *(const frag8*)&sB[(mbase + lrow) * LDB + kb * 32 + quad * 8];
        #pragma unroll
        for (int nt = 0; nt < 8; ++nt) {
            frag8 b = *(const frag8*)&sW[(nt * 16 + lrow) * LDA + kb * 32 + quad * 8];
            acc[nt] = __builtin_amdgcn_mfma_f32_16x16x32_bf16(a, b, acc[nt], 0, 0, 0);
        }
    }
    {
        int le = wave * 4 + quad;          // C row = mbase + quad*4 + r  ->  le, t=r
        int e = e0 + le;
        bool valid = e < E;
        int node = sNode[le];
        float* mb = m_i + (size_t)node * 512;
        #pragma unroll
        for (int nt = 0; nt < 8; ++nt) {
            int col = nt * 16 + lrow;
            float bias = b2[col];
            #pragma unroll
            for (int r = 0; r < 4; ++r) {
                float v = silu_f(acc[nt][r] + bias);
                sA[(mbase + quad * 4 + r) * LDA + col] = f2b(v);
                if (valid) atomicAdd(mb + col * 4 + r, v);
            }
        }
    }
    __syncthreads();
    // install cw1
    #pragma unroll
    for (int i = 0; i < 4; ++i) {
        int c = tid + i * 512;
        *(uint4*)&sW[(c >> 4) * LDA + (c & 15) * 8] = wp[i];
    }
    __syncthreads();

    // ---- coord layer: c1 = silu(y2 @ cw1 + cb1); c = (c1 . cw2 + cb2) / (sqrt(n2+eps)+1) ----
    #pragma unroll
    for (int nt = 0; nt < 8; ++nt) acc[nt] = (f32x4){0.f, 0.f, 0.f, 0.f};
    #pragma unroll
    for (int kb = 0; kb < 4; ++kb) {
        frag8 a = *(const frag8*)&sA[(mbase + lrow) * LDA + kb * 32 + quad * 8];
        #pragma unroll
        for (int nt = 0; nt < 8; ++nt) {
            frag8 b = *(const frag8*)&sW[(nt * 16 + lrow) * LDA + kb * 32 + quad * 8];
            acc[nt] = __builtin_amdgcn_mfma_f32_16x16x32_bf16(a, b, acc[nt], 0, 0, 0);
        }
    }
    {
        float part[4] = {0.f, 0.f, 0.f, 0.f};
        #pragma unroll
        for (int nt = 0; nt < 8; ++nt) {
            int col = nt * 16 + lrow;
            float bias = cb1[col];
            float w = cw2[col];
            #pragma unroll
            for (int r = 0; r < 4; ++r)
                part[r] += silu_f(acc[nt][r] + bias) * w;
        }
        #pragma unroll
        for (int off = 1; off < 16; off <<= 1) {
            #pragma unroll
            for (int r = 0; r < 4; ++r)
                part[r] += __shfl_xor(part[r], off);
        }
        if (lrow == 0) {
            int le = wave * 4 + quad;
            int e = e0 + le;
            if (e < E) {
                int node = sNode[le];
                float cb2f = cb2[0];
                #pragma unroll
                for (int r = 0; r < 4; ++r) {
                    float n2 = sNorm[le * 4 + r];
                    float c = (part[r] + cb2f) / (sqrtf(n2 + EPSF) + 1.f);
                    atomicAdd(&agg[(size_t)node * 12 + 0 + r], c * sXij[le * 12 + 0 + r]);
                    atomicAdd(&agg[(size_t)node * 12 + 4 + r], c * sXij[le * 12 + 4 + r]);
                    atomicAdd(&agg[(size_t)node * 12 + 8 + r], c * sXij[le * 12 + 8 + r]);
                }
                atomicAdd(&cnt[node], 1.f);
            }
        }
    }
}

// ---------------- node kernel: 32 nodes (128 rows), K=192 -> 128 -> 64 ----------------
__global__ __launch_bounds__(512, 1)
void node_kernel(const float* __restrict__ h, const float* __restrict__ m_i,
                 const unsigned short* __restrict__ nw1b,
                 const unsigned short* __restrict__ nw2b,
                 const float* __restrict__ nb1, const float* __restrict__ nb2,
                 float* __restrict__ out_h, int N)
{
    __shared__ unsigned short sA[128 * LDAN];
    __shared__ unsigned short sW[128 * LDAN];
    __shared__ unsigned short sB[128 * LDB];

    const int tid = threadIdx.x;
    const int n0  = blockIdx.x * N_NODES;

    for (int c = tid; c < 3072; c += 512) {            // nw1: 128 rows x 24 chunks
        int row = c / 24, kc = (c - row * 24) * 8;
        *(uint4*)&sW[row * LDAN + kc] = *(const uint4*)&nw1b[row * 192 + kc];
    }
    if (tid < 256) {                                    // h -> k 0..63
        int ln = tid >> 3, d0 = (tid & 7) * 8;
        int node = n0 + ln;
        if (node < N) {
            const float4* hp = (const float4*)(h + (size_t)node * 256);
            float4 hv[8];
            #pragma unroll
            for (int q = 0; q < 8; ++q) hv[q] = hp[d0 + q];
            #pragma unroll
            for (int t = 0; t < 4; ++t) {
                float vv[8];
                #pragma unroll
                for (int q = 0; q < 8; ++q) vv[q] = ((const float*)&hv[q])[t];
                *(uint4*)&sA[(ln * 4 + t) * LDAN + d0] = pk8(vv);
            }
        }
    }
    for (int c = tid; c < 1024; c += 512) {             // m_i -> k 64..191
        int ln = c >> 5, hd0 = (c & 31) * 4;
        int node = n0 + ln;
        if (node < N) {
            const float4* mp = (const float4*)(m_i + (size_t)node * 512);
            float4 mv[4];
            #pragma unroll
            for (int q = 0; q < 4; ++q) mv[q] = mp[hd0 + q];
            #pragma unroll
            for (int t = 0; t < 4; ++t) {
                uint2 u;
                u.x = pk2(((const float*)&mv[0])[t], ((const float*)&mv[1])[t]);
                u.y = pk2(((const float*)&mv[2])[t], ((const float*)&mv[3])[t]);
                *(uint2*)&sA[(ln * 4 + t) * LDAN + 64 + hd0] = u;
            }
        }
    }
    uint4 wp[2];
    #pragma unroll
    for (int i = 0; i < 2; ++i) {                       // prefetch nw2 (1024 chunks)
        int c = tid + i * 512;
        wp[i] = *(const uint4*)&nw2b[(c >> 4) * 128 + (c & 15) * 8];
    }
    __syncthreads();

    const int lane = tid & 63;
    const int wave = tid >> 6;
    const int lrow = lane & 15;
    const int quad = lane >> 4;
    const int mbase = wave * 16;

    f32x4 acc[8];
    #pragma unroll
    for (int nt = 0; nt < 8; ++nt) acc[nt] = (f32x4){0.f, 0.f, 0.f, 0.f};
    #pragma unroll
    for (int kb = 0; kb < 6; ++kb) {
        frag8 a = *(const frag8*)&sA[(mbase + lrow) * LDAN + kb * 32 + quad * 8];
        #pragma unroll
        for (int nt = 0; nt < 8; ++nt) {
            frag8 b = *(const frag8*)&sW[(nt * 16 + lrow) * LDAN + kb * 32 + quad * 8];
            acc[nt] = __builtin_amdgcn_mfma_f32_16x16x32_bf16(a, b, acc[nt], 0, 0, 0);
        }
    }
    #pragma unroll
    for (int nt = 0; nt < 8; ++nt) {
        int col = nt * 16 + lrow;
        float bias = nb1[col];
        #pragma unroll
        for (int r = 0; r < 4; ++r)
            sB[(mbase + quad * 4 + r) * LDB + col] = f2b(silu_f(acc[nt][r] + bias));
    }
    __syncthreads();
    #pragma unroll
    for (int i = 0; i < 2; ++i) {
        int c = tid + i * 512;
        *(uint4*)&sW[(c >> 4) * LDAN + (c & 15) * 8] = wp[i];
    }
    __syncthreads();

    f32x4 acc2[4];
    #pragma unroll
    for (int nt = 0; nt < 4; ++nt) acc2[nt] = (f32x4){0.f, 0.f, 0.f, 0.f};
    #pragma unroll
    for (int kb = 0; kb < 4; ++kb) {
        frag8 a = *(const frag8*)&sB[(mbase + lrow) * LDB + kb * 32 + quad * 8];
        #pragma unroll
        for (int nt = 0; nt < 4; ++nt) {
            frag8 b = *(const frag8*)&sW[(nt * 16 + lrow) * LDAN + kb * 32 + quad * 8];
            acc2[nt] = __builtin_amdgcn_mfma_f32_16x16x32_bf16(a, b, acc2[nt], 0, 0, 0);
        }
    }
    {
        int ln = wave * 4 + quad;
        int node = n0 + ln;
        if (node < N) {
            float* op = out_h + (size_t)node * 256;
            #pragma unroll
            for (int nt = 0; nt < 4; ++nt) {
                int col = nt * 16 + lrow;
                float bias = nb2[col];
                float4 ov = { acc2[nt][0] + bias, acc2[nt][1] + bias,
                              acc2[nt][2] + bias, acc2[nt][3] + bias };
                *(float4*)&op[col * 4] = ov;
            }
        }
    }
}

// ---------------- coord update ----------------
__global__ void coord_update(const float* __restrict__ x, const float* __restrict__ agg,
                             const float* __restrict__ cnt, float* __restrict__ out_x, int N)
{
    int i = blockIdx.x * 256 + threadIdx.x;
    if (i < N * 12) {
        int n = i / 12;
        out_x[i] = x[i] + agg[i] / fmaxf(cnt[n], 1.f);
    }
}

extern "C" void kernel_launch(void* const* d_in, const int* in_sizes, int n_in,
                              void* d_out, int out_size, void* d_ws, size_t ws_size,
                              hipStream_t stream)
{
    const float* x   = (const float*)d_in[0];
    const float* h   = (const float*)d_in[1];
    const int*   ei  = (const int*)d_in[2];
    const float* ea  = (const float*)d_in[3];
    const float* w1  = (const float*)d_in[5];
    const float* b1  = (const float*)d_in[6];
    const float* w2  = (const float*)d_in[7];
    const float* b2  = (const float*)d_in[8];
    const float* cw1 = (const float*)d_in[9];
    const float* cb1 = (const float*)d_in[10];
    const float* cw2 = (const float*)d_in[11];
    const float* cb2 = (const float*)d_in[12];
    const float* nw1 = (const float*)d_in[13];
    const float* nb1 = (const float*)d_in[14];
    const float* nw2 = (const float*)d_in[15];
    const float* nb2 = (const float*)d_in[16];

    const int N = in_sizes[0] / 12;
    const int E = in_sizes[2] / 2;

    unsigned short* wb = (unsigned short*)d_ws;
    const unsigned short* w1b  = wb;
    const unsigned short* w2b  = wb + 20480;
    const unsigned short* cw1b = wb + 36864;
    const unsigned short* nw1b = wb + 53248;
    const unsigned short* nw2b = wb + 77824;

    float* m_i = (float*)((char*)d_ws + 172032);
    float* agg = m_i + (size_t)N * 512;
    float* cnt = agg + (size_t)N * 12;

    hipMemsetAsync(m_i, 0, (size_t)N * 525 * sizeof(float), stream);
    prep_weights<<<336, 256, 0, stream>>>(w1, w2, cw1, nw1, nw2, wb);

    float* out_x = (float*)d_out;
    float* out_h = out_x + (size_t)N * 12;

    edge_kernel<<<(E + E_EDGES - 1) / E_EDGES, 512, 0, stream>>>(
        x, h, ei, ea, w1b, w2b, cw1b, b1, b2, cb1, cb2, cw2, m_i, agg, cnt, N, E);
    node_kernel<<<(N + N_NODES - 1) / N_NODES, 512, 0, stream>>>(
        h, m_i, nw1b, nw2b, nb1, nb2, out_h, N);
    coord_update<<<(N * 12 + 255) / 256, 256, 0, stream>>>(x, agg, cnt, out_x, N);
}